// Round 3
// baseline (446.209 us; speedup 1.0000x reference)
//
#include <hip/hip_runtime.h>

#define B_ 256
#define T_ 1024
#define V_ 5000
#define D_ 100
#define H_ 64
#define C_ 2

// ---------------------------------------------------------------------------
// Kernel 1: EW[v][h] = sum_d E[v][d] * W[d][h] + b[h]
// ---------------------------------------------------------------------------
__global__ __launch_bounds__(256) void ew_kernel(const float* __restrict__ E,
                                                 const float* __restrict__ W,
                                                 const float* __restrict__ bias,
                                                 float* __restrict__ EW) {
    int idx = blockIdx.x * 256 + threadIdx.x;   // 0 .. V_*H_
    if (idx >= V_ * H_) return;
    int h = idx & (H_ - 1);
    int v = idx >> 6;
    float acc = bias[h];
    const float* Erow = E + v * D_;
    #pragma unroll 4
    for (int d = 0; d < D_; ++d) {
        acc = fmaf(Erow[d], W[d * H_ + h], acc);
    }
    EW[idx] = acc;
}

// ---------------------------------------------------------------------------
// Kernel 2: per-batch RNN. One wave (64 lanes) per batch element.
// Lane j holds h[j] and U[:,j] in VGPRs; h[i] broadcast via v_readlane.
//
// R1/R2 post-mortem: the compiler rematerialized U loads inside the T-loop
// (VGPR_Count=44, FETCH=5.6GB, 850 cyc/step). Fixes:
//  - asm volatile "+v" barrier on each loaded U value: the value is defined
//    by a volatile asm the compiler cannot re-execute -> must stay in VGPR.
//  - __launch_bounds__(64, 1): min 1 wave/EU -> ~512 VGPR budget, no
//    pressure to spill the 64 live Ucol registers.
// ---------------------------------------------------------------------------
__device__ __forceinline__ float readlane_f(float v, int lane) {
    return __uint_as_float(__builtin_amdgcn_readlane(__float_as_uint(v), lane));
}

__global__ __launch_bounds__(64, 1) void rnn_kernel(const int* __restrict__ tokens,
                                                    const float* __restrict__ EW,
                                                    const float* __restrict__ U,
                                                    const float* __restrict__ Wd,
                                                    const float* __restrict__ bd,
                                                    float* __restrict__ out) {
    const int b = blockIdx.x;     // batch element
    const int j = threadIdx.x;    // 0..63 : hidden unit

    // U column j pinned in VGPRs (see header comment).
    float Ucol[H_];
    #pragma unroll
    for (int i = 0; i < H_; ++i) {
        float u = U[i * H_ + j];
        asm volatile("" : "+v"(u));   // opaque def: kills rematerialization
        Ucol[i] = u;
    }

    const int* tok = tokens + b * T_;

    float h = 0.f;
    float pooled = 0.f;

    // token chunk: lane l holds tok[chunk*64 + l]; refreshed every 64 steps
    int tchunk = tok[j];
    int cur_tok = __builtin_amdgcn_readlane(tchunk, 0);
    float xw = EW[cur_tok * H_ + j];   // prefetched xw for step 0

    for (int t = 0; t < T_; ++t) {
        // ---- prefetch step t+1 (overlaps with the dot below) ----
        int nt = t + 1;
        int next_tok = 0;
        float xw_next = 0.f;
        if (nt < T_) {
            if ((nt & 63) == 0) tchunk = tok[nt + j];       // uniform branch
            next_tok = __builtin_amdgcn_readlane(tchunk, nt & 63);
            xw_next = EW[next_tok * H_ + j];                // coalesced, L2-hit
        }

        // ---- dot: sum_i h[i] * U[i][j], 4 independent fma chains ----
        float a0 = 0.f, a1 = 0.f, a2 = 0.f, a3 = 0.f;
        #pragma unroll
        for (int i = 0; i < H_; i += 4) {
            a0 = fmaf(readlane_f(h, i + 0), Ucol[i + 0], a0);
            a1 = fmaf(readlane_f(h, i + 1), Ucol[i + 1], a1);
            a2 = fmaf(readlane_f(h, i + 2), Ucol[i + 2], a2);
            a3 = fmaf(readlane_f(h, i + 3), Ucol[i + 3], a3);
        }
        // xw added last: dot starts without waiting on the gather's vmcnt
        float x = ((a0 + a1) + (a2 + a3)) + xw;

        // ---- fast tanh: (e^{2x}-1)*rcp(e^{2x}+1), clamped ----
        x = fminf(fmaxf(x, -15.f), 15.f);
        float e = __expf(2.f * x);
        float hn = (e - 1.f) * __builtin_amdgcn_rcpf(e + 1.f);

        // Keras mask_zero: masked step carries previous state
        h = (cur_tok != 0) ? hn : h;
        pooled += h;   // unmasked mean over time

        cur_tok = next_tok;
        xw = xw_next;
    }

    // ---- epilogue: pooled mean -> dense(2) -> sigmoid ----
    float p = pooled * (1.0f / (float)T_);
    float v0 = p * Wd[j * C_ + 0];
    float v1 = p * Wd[j * C_ + 1];
    #pragma unroll
    for (int off = 32; off >= 1; off >>= 1) {
        v0 += __shfl_down(v0, off, 64);
        v1 += __shfl_down(v1, off, 64);
    }
    if (j == 0) {
        float l0 = v0 + bd[0];
        float l1 = v1 + bd[1];
        out[b * C_ + 0] = 1.f / (1.f + __expf(-l0));
        out[b * C_ + 1] = 1.f / (1.f + __expf(-l1));
    }
}

// ---------------------------------------------------------------------------
extern "C" void kernel_launch(void* const* d_in, const int* in_sizes, int n_in,
                              void* d_out, int out_size, void* d_ws, size_t ws_size,
                              hipStream_t stream) {
    const int*   tokens = (const int*)  d_in[0];  // [B,T] int32
    const float* E      = (const float*)d_in[1];  // [V,D]
    const float* W      = (const float*)d_in[2];  // [D,H]
    const float* U      = (const float*)d_in[3];  // [H,H]
    const float* bias   = (const float*)d_in[4];  // [H]
    const float* Wd     = (const float*)d_in[5];  // [H,C]
    const float* bd     = (const float*)d_in[6];  // [C]
    float* out = (float*)d_out;                   // [B,C]
    float* EW  = (float*)d_ws;                    // [V,H] scratch: 1.28 MB

    ew_kernel<<<(V_ * H_ + 255) / 256, 256, 0, stream>>>(E, W, bias, EW);
    rnn_kernel<<<B_, H_, 0, stream>>>(tokens, EW, U, Wd, bd, out);
}

// Round 4
// 340.232 us; speedup vs baseline: 1.3115x; 1.3115x over previous
//
#include <hip/hip_runtime.h>

#define B_ 256
#define T_ 1024
#define V_ 5000
#define D_ 100
#define H_ 64
#define C_ 2

// ---------------------------------------------------------------------------
// Kernel 1: EW[v][h] = sum_d E[v][d] * W[d][h] + b[h]
// ---------------------------------------------------------------------------
__global__ __launch_bounds__(256) void ew_kernel(const float* __restrict__ E,
                                                 const float* __restrict__ W,
                                                 const float* __restrict__ bias,
                                                 float* __restrict__ EW) {
    int idx = blockIdx.x * 256 + threadIdx.x;   // 0 .. V_*H_
    if (idx >= V_ * H_) return;
    int h = idx & (H_ - 1);
    int v = idx >> 6;
    float acc = bias[h];
    const float* Erow = E + v * D_;
    #pragma unroll 4
    for (int d = 0; d < D_; ++d) {
        acc = fmaf(Erow[d], W[d * H_ + h], acc);
    }
    EW[idx] = acc;
}

// ---------------------------------------------------------------------------
// Kernel 2: per-batch RNN. One wave (64 lanes) per batch element.
//
// R1-R3 post-mortem: the register allocator refuses to keep a 64-element
// per-lane U column live across the T-loop (remats the global loads or
// spills to scratch -> 16 KB/wave/step of uncacheable traffic = 5.6 GB
// FETCH, 886 cyc/step). Fix: stop asking for it. U lives in LDS with a
// rotation-swizzled transposed layout:
//   - lane j's column is contiguous -> ds_read_b128 (16B aligned)
//   - chunk c of lane j stored at position (c+j)&15 -> for a fixed c the
//     64 lanes' reads are spread evenly over banks (8 words/bank = b128
//     baseline, no extra conflict)
// Values are consumed 4-at-a-time and immediately dead -> ~50 live VGPRs,
// nothing to spill. h broadcast stays v_readlane (no LDS latency on the
// serial chain). Tokens preloaded to LDS, read as wave-uniform broadcast.
// ---------------------------------------------------------------------------
__device__ __forceinline__ float readlane_f(float v, int lane) {
    return __uint_as_float(__builtin_amdgcn_readlane(__float_as_uint(v), lane));
}

__global__ __launch_bounds__(64, 1) void rnn_kernel(const int* __restrict__ tokens,
                                                    const float* __restrict__ EW,
                                                    const float* __restrict__ U,
                                                    const float* __restrict__ Wd,
                                                    const float* __restrict__ bd,
                                                    float* __restrict__ out) {
    const int b = blockIdx.x;     // batch element
    const int j = threadIdx.x;    // 0..63 : hidden unit

    __shared__ float sh_U[H_ * H_];   // 16 KB, swizzled: see header
    __shared__ int   sh_tok[T_];      // 4 KB

    // ---- preload U (transposed + rotation swizzle) and tokens ----
    #pragma unroll 8
    for (int i = 0; i < H_; ++i) {
        float u = U[i * H_ + j];                 // coalesced across lanes
        int p = ((i >> 2) + j) & 15;             // rotated chunk position
        sh_U[(j << 6) + (p << 2) + (i & 3)] = u;
    }
    const int* tok = tokens + b * T_;
    #pragma unroll
    for (int k = 0; k < T_ / H_; ++k) {
        sh_tok[k * H_ + j] = tok[k * H_ + j];    // coalesced
    }
    __syncthreads();

    float h = 0.f;
    float pooled = 0.f;

    int cur_tok = sh_tok[0];                     // uniform broadcast read
    float xw = EW[cur_tok * H_ + j];             // prefetched xw for step 0

    for (int t = 0; t < T_; ++t) {
        // ---- prefetch step t+1 (independent: issues early, L2-hit) ----
        int nt = t + 1;
        int next_tok = 0;
        float xw_next = 0.f;
        if (nt < T_) {
            next_tok = sh_tok[nt];               // uniform broadcast
            xw_next = EW[next_tok * H_ + j];     // coalesced gather
        }

        // ---- dot: sum_i h[i] * U[i][j], 4 independent fma chains ----
        // U chunks stream from LDS (b128, bank-balanced); h[i] broadcast
        // via readlane from the single h register.
        float a0 = 0.f, a1 = 0.f, a2 = 0.f, a3 = 0.f;
        #pragma unroll
        for (int c = 0; c < 16; ++c) {
            int p = (c + j) & 15;                // loop-invariant per c
            const float4 u4 =
                *(const float4*)&sh_U[(j << 6) + (p << 2)];
            a0 = fmaf(readlane_f(h, 4 * c + 0), u4.x, a0);
            a1 = fmaf(readlane_f(h, 4 * c + 1), u4.y, a1);
            a2 = fmaf(readlane_f(h, 4 * c + 2), u4.z, a2);
            a3 = fmaf(readlane_f(h, 4 * c + 3), u4.w, a3);
        }
        float x = ((a0 + a1) + (a2 + a3)) + xw;

        // ---- fast tanh: (e^{2x}-1)*rcp(e^{2x}+1), clamped ----
        x = fminf(fmaxf(x, -15.f), 15.f);
        float e = __expf(2.f * x);
        float hn = (e - 1.f) * __builtin_amdgcn_rcpf(e + 1.f);

        // Keras mask_zero: masked step carries previous state
        h = (cur_tok != 0) ? hn : h;
        pooled += h;   // unmasked mean over time

        cur_tok = next_tok;
        xw = xw_next;
    }

    // ---- epilogue: pooled mean -> dense(2) -> sigmoid ----
    float p = pooled * (1.0f / (float)T_);
    float v0 = p * Wd[j * C_ + 0];
    float v1 = p * Wd[j * C_ + 1];
    #pragma unroll
    for (int off = 32; off >= 1; off >>= 1) {
        v0 += __shfl_down(v0, off, 64);
        v1 += __shfl_down(v1, off, 64);
    }
    if (j == 0) {
        float l0 = v0 + bd[0];
        float l1 = v1 + bd[1];
        out[b * C_ + 0] = 1.f / (1.f + __expf(-l0));
        out[b * C_ + 1] = 1.f / (1.f + __expf(-l1));
    }
}

// ---------------------------------------------------------------------------
extern "C" void kernel_launch(void* const* d_in, const int* in_sizes, int n_in,
                              void* d_out, int out_size, void* d_ws, size_t ws_size,
                              hipStream_t stream) {
    const int*   tokens = (const int*)  d_in[0];  // [B,T] int32
    const float* E      = (const float*)d_in[1];  // [V,D]
    const float* W      = (const float*)d_in[2];  // [D,H]
    const float* U      = (const float*)d_in[3];  // [H,H]
    const float* bias   = (const float*)d_in[4];  // [H]
    const float* Wd     = (const float*)d_in[5];  // [H,C]
    const float* bd     = (const float*)d_in[6];  // [C]
    float* out = (float*)d_out;                   // [B,C]
    float* EW  = (float*)d_ws;                    // [V,H] scratch: 1.28 MB

    ew_kernel<<<(V_ * H_ + 255) / 256, 256, 0, stream>>>(E, W, bias, EW);
    rnn_kernel<<<B_, H_, 0, stream>>>(tokens, EW, U, Wd, bd, out);
}

// Round 5
// 309.930 us; speedup vs baseline: 1.4397x; 1.0978x over previous
//
#include <hip/hip_runtime.h>

#define B_ 256
#define T_ 1024
#define V_ 5000
#define D_ 100
#define H_ 64
#define C_ 2

// ---------------------------------------------------------------------------
// Kernel 1: EW[v][h] = sum_d E[v][d] * W[d][h] + b[h]
// ---------------------------------------------------------------------------
__global__ __launch_bounds__(256) void ew_kernel(const float* __restrict__ E,
                                                 const float* __restrict__ W,
                                                 const float* __restrict__ bias,
                                                 float* __restrict__ EW) {
    int idx = blockIdx.x * 256 + threadIdx.x;   // 0 .. V_*H_
    if (idx >= V_ * H_) return;
    int h = idx & (H_ - 1);
    int v = idx >> 6;
    float acc = bias[h];
    const float* Erow = E + v * D_;
    #pragma unroll 4
    for (int d = 0; d < D_; ++d) {
        acc = fmaf(Erow[d], W[d * H_ + h], acc);
    }
    EW[idx] = acc;
}

// ---------------------------------------------------------------------------
// Kernel 2: per-batch RNN. One wave per batch element. 632 cyc/step in R4;
// ~233 VALU insts/step (VALUBusy 18.5/25). This round strips the loop to
// its floor (~145 insts/step):
//  - 16 swizzled LDS indices precomputed BEFORE the T-loop (were ~48
//    VALU/step of recomputed (c+j)&15 + shifts; now 16 loop-invariant regs)
//  - sh_tok padded by 2 zeros -> no `t+2 < T` guard / cndmasks
//  - T-loop unrolled x2 with a 2-step xw prefetch pipeline (~700 cyc ahead,
//    covers L2 latency; kills loop-carried copies)
//  - clampless tanh: hn = 1 - 2*rcp(e+1); e=inf -> 1, e=0 -> -1, no NaN
// NOTE (R1-R4 lesson): FETCH_SIZE is KB not MB -- 5.6 MB = input footprint.
// The R1-R3 stall was remat/spill latency, not HBM traffic. Only the serial
// per-step instruction count matters now; parallel prework is free.
// ---------------------------------------------------------------------------
__device__ __forceinline__ float readlane_f(float v, int lane) {
    return __uint_as_float(__builtin_amdgcn_readlane(__float_as_uint(v), lane));
}

__global__ __launch_bounds__(64, 1) void rnn_kernel(const int* __restrict__ tokens,
                                                    const float* __restrict__ EW,
                                                    const float* __restrict__ U,
                                                    const float* __restrict__ Wd,
                                                    const float* __restrict__ bd,
                                                    float* __restrict__ out) {
    const int b = blockIdx.x;     // batch element
    const int j = threadIdx.x;    // 0..63 : hidden unit

    // U columns, swizzled: lane j's column contiguous as 16 float4 chunks;
    // chunk c stored at slot (c+j)&15 -> b128 reads bank-balanced.
    __shared__ float4 sh_U4[H_ * 16];   // 16 KB
    __shared__ int    sh_tok[T_ + 2];   // 4 KB + pad

    float* sh_Uf = (float*)sh_U4;
    #pragma unroll 8
    for (int i = 0; i < H_; ++i) {
        float u = U[i * H_ + j];                 // coalesced across lanes
        int p = ((i >> 2) + j) & 15;             // rotated chunk slot
        sh_Uf[(j << 6) + (p << 2) + (i & 3)] = u;
    }
    const int* tok = tokens + b * T_;
    #pragma unroll
    for (int k = 0; k < T_ / H_; ++k) {
        sh_tok[k * H_ + j] = tok[k * H_ + j];    // coalesced
    }
    if (j < 2) sh_tok[T_ + j] = 0;               // pad: kills tail guard
    __syncthreads();

    // Loop-invariant swizzled indices (16 VGPRs) — NOT recomputed per step.
    int uidx[16];
    #pragma unroll
    for (int c = 0; c < 16; ++c) uidx[c] = (j << 4) + ((c + j) & 15);

    float h = 0.f;
    float pooled = 0.f;

    // 2-step-deep xw prefetch pipeline
    int2 tkA = *(const int2*)&sh_tok[0];
    float xw0 = EW[tkA.x * H_ + j];
    float xw1 = EW[tkA.y * H_ + j];

    // one recurrence step: dot + clampless tanh + mask + pool
    #define RNN_STEP(tokv, xwv)                                          \
    {                                                                    \
        float a0 = 0.f, a1 = 0.f, a2 = 0.f, a3 = 0.f;                    \
        _Pragma("unroll")                                                \
        for (int c = 0; c < 16; ++c) {                                   \
            const float4 u4 = sh_U4[uidx[c]];                            \
            a0 = fmaf(readlane_f(h, 4 * c + 0), u4.x, a0);               \
            a1 = fmaf(readlane_f(h, 4 * c + 1), u4.y, a1);               \
            a2 = fmaf(readlane_f(h, 4 * c + 2), u4.z, a2);               \
            a3 = fmaf(readlane_f(h, 4 * c + 3), u4.w, a3);               \
        }                                                                \
        float x = ((a0 + a1) + (a2 + a3)) + (xwv);                       \
        float e = __expf(2.f * x);                                       \
        float r = __builtin_amdgcn_rcpf(e + 1.f);                        \
        float hn = fmaf(-2.f, r, 1.f);                                   \
        h = ((tokv) != 0) ? hn : h;                                      \
        pooled += h;                                                     \
    }

    for (int t = 0; t < T_; t += 2) {
        // prefetch steps t+2, t+3 (pad makes the tail read safe: EW[0])
        int2 tkB = *(const int2*)&sh_tok[t + 2];
        float xw2 = EW[tkB.x * H_ + j];
        float xw3 = EW[tkB.y * H_ + j];

        RNN_STEP(tkA.x, xw0);
        RNN_STEP(tkA.y, xw1);

        tkA = tkB;
        xw0 = xw2;
        xw1 = xw3;
    }
    #undef RNN_STEP

    // ---- epilogue: pooled mean -> dense(2) -> sigmoid ----
    float p = pooled * (1.0f / (float)T_);
    float v0 = p * Wd[j * C_ + 0];
    float v1 = p * Wd[j * C_ + 1];
    #pragma unroll
    for (int off = 32; off >= 1; off >>= 1) {
        v0 += __shfl_down(v0, off, 64);
        v1 += __shfl_down(v1, off, 64);
    }
    if (j == 0) {
        float l0 = v0 + bd[0];
        float l1 = v1 + bd[1];
        out[b * C_ + 0] = 1.f / (1.f + __expf(-l0));
        out[b * C_ + 1] = 1.f / (1.f + __expf(-l1));
    }
}

// ---------------------------------------------------------------------------
extern "C" void kernel_launch(void* const* d_in, const int* in_sizes, int n_in,
                              void* d_out, int out_size, void* d_ws, size_t ws_size,
                              hipStream_t stream) {
    const int*   tokens = (const int*)  d_in[0];  // [B,T] int32
    const float* E      = (const float*)d_in[1];  // [V,D]
    const float* W      = (const float*)d_in[2];  // [D,H]
    const float* U      = (const float*)d_in[3];  // [H,H]
    const float* bias   = (const float*)d_in[4];  // [H]
    const float* Wd     = (const float*)d_in[5];  // [H,C]
    const float* bd     = (const float*)d_in[6];  // [C]
    float* out = (float*)d_out;                   // [B,C]
    float* EW  = (float*)d_ws;                    // [V,H] scratch: 1.28 MB

    ew_kernel<<<(V_ * H_ + 255) / 256, 256, 0, stream>>>(E, W, bias, EW);
    rnn_kernel<<<B_, H_, 0, stream>>>(tokens, EW, U, Wd, bd, out);
}